// Round 8
// baseline (237.245 us; speedup 1.0000x reference)
//
#include <hip/hip_runtime.h>
#include <hip/hip_fp16.h>
#include <cstdint>
#include <cstddef>

// Problem constants (fixed by reference setup_inputs)
#define EMBED  256
#define NV_PER_B 13294
#define M_PAD   26624          // 416 * 64
#define NQPB   8               // queries per msda block

// Spatial pyramid (structural constants from reference SHAPES)
__constant__ const int c_H[4]  = {100, 50, 25, 13};
__constant__ const int c_W[4]  = {100, 50, 25, 13};
__constant__ const int c_ST[4] = {0, 10000, 12500, 13125};

typedef _Float16 f16x8 __attribute__((ext_vector_type(8)));
typedef float f32x4 __attribute__((ext_vector_type(4)));

#define GLDS(g, l) __builtin_amdgcn_global_load_lds( \
    (const __attribute__((address_space(1))) void*)(g), \
    (__attribute__((address_space(3))) void*)(l), 16, 0, 0)

// Tiled fp16 layout for GEMM operands: rows grouped in 64-row tiles;
// halves offset = tile*16384 + kc*2048 + g*512 + row*8  (kc = k/32, g = (k/8)&3)
// -> GLDS inst (kc,g) reads contiguous 1KB; LDS image is k-major so frag
//    ds_read_b128 is lane-contiguous (conflict-free).

// ---------------- convert: fp32 -> tiled fp16 (q, v, weights) ----------------
__global__ __launch_bounds__(256) void convert_kernel(
    const float* __restrict__ q,  const float* __restrict__ v,
    const float* __restrict__ wv, const float* __restrict__ wsamp,
    const float* __restrict__ wattn, const float* __restrict__ wo,
    const float* __restrict__ bsamp, const float* __restrict__ battn,
    __half* __restrict__ q_t, __half* __restrict__ v_t,
    __half* __restrict__ wv_t, __half* __restrict__ wcat_t,
    __half* __restrict__ wo_h, float* __restrict__ biascat, int M)
{
    __shared__ float ls[64][36];   // 36-stride: 16B-aligned rows, conflict-light
    const int id = blockIdx.x, t = threadIdx.x;

    if (id < 6736) {
        // tiled convert of one (array, tile, kc)
        const float* srcA; const float* srcB = nullptr;
        __half* dst; int tile, kc, vrows, part2 = 0;
        if (id < 6656) {           // q/v: 2 arrays x 416 tiles x 8 kc
            const int arr = id & 1, r = id >> 1;
            tile = r >> 3; kc = r & 7;
            srcA = arr ? v : q; dst = arr ? v_t : q_t; vrows = M;
        } else if (id < 6688) {    // W_val: 4 tiles x 8 kc
            const int r = id - 6656;
            tile = r >> 3; kc = r & 7;
            srcA = wv; dst = wv_t; vrows = 256;
        } else {                   // W_cat = [W_samp;W_attn]: 6 tiles x 8 kc
            const int r = id - 6688;
            tile = r >> 3; kc = r & 7;
            srcA = wsamp; srcB = wattn; dst = wcat_t; vrows = 384; part2 = 1;
        }
        const int row = t >> 2, kq = t & 3;
        const int gr = tile * 64 + row;
        float4 a = make_float4(0.f, 0.f, 0.f, 0.f);
        float4 b = make_float4(0.f, 0.f, 0.f, 0.f);
        if (gr < vrows) {
            const float* sp = (part2 && gr >= 256) ? (srcB + (size_t)(gr - 256) * 256)
                                                   : (srcA + (size_t)gr * 256);
            a = *(const float4*)(sp + kc * 32 + kq * 8);
            b = *(const float4*)(sp + kc * 32 + kq * 8 + 4);
        }
        *(float4*)&ls[row][kq * 8]     = a;
        *(float4*)&ls[row][kq * 8 + 4] = b;
        __syncthreads();
        const int g = t >> 6, r2 = t & 63;
        __align__(16) __half h8[8];
        #pragma unroll
        for (int j = 0; j < 8; ++j) h8[j] = __float2half(ls[r2][g * 8 + j]);
        *(int4*)(dst + (size_t)tile * 16384 + kc * 2048 + g * 512 + r2 * 8) = *(const int4*)h8;
    } else if (id < 6768) {
        // W_out: plain row-major fp16 (consumed as direct A-frags in msda)
        const int i = (id - 6736) * 256 + t;   // [0, 8192)
        const float4 a = ((const float4*)wo)[i * 2];
        const float4 b = ((const float4*)wo)[i * 2 + 1];
        __align__(16) __half h8[8];
        h8[0] = __float2half(a.x); h8[1] = __float2half(a.y);
        h8[2] = __float2half(a.z); h8[3] = __float2half(a.w);
        h8[4] = __float2half(b.x); h8[5] = __float2half(b.y);
        h8[6] = __float2half(b.z); h8[7] = __float2half(b.w);
        *(int4*)(wo_h + (size_t)i * 8) = *(const int4*)h8;
    } else {
        if (t < 96) {   // bias_cat = [b_samp(256); b_attn(128)]
            const float4 a = (t < 64) ? ((const float4*)bsamp)[t]
                                      : ((const float4*)battn)[t - 64];
            ((float4*)biascat)[t] = a;
        }
    }
}

// ---------------- proj GEMM: barrier-free, tiled GLDS, conflict-free LDS ----------------
// grid.y: 0,1 -> value@W_val -> vproj (fp16); 2,3,4 -> query@W_cat -> qo (fp16)
__global__ __launch_bounds__(256) void proj_gemm_kernel(
    const __half* __restrict__ q_t, const __half* __restrict__ v_t,
    const __half* __restrict__ wv_t, const __half* __restrict__ wcat_t,
    const float* __restrict__ b_val, const float* __restrict__ biascat,
    __half* __restrict__ vproj, __half* __restrict__ qo)
{
    __shared__ __align__(16) char smem[65536];   // 4 waves x 2 stages x 8KB
    const int t = threadIdx.x;
    const int wave = t >> 6, lane = t & 63;
    const int lr16 = lane & 15, qk = lane >> 4;
    const int wrow = wave & 1, wcol = wave >> 1;
    const int y = blockIdx.y, bx = blockIdx.x;

    const __half* At; const __half* Bt; const float* bias; __half* Cc; int Nst, tb;
    if (y < 2) { At = v_t; Bt = wv_t;   bias = b_val;   Cc = vproj; Nst = 256; tb = y * 2 + wcol; }
    else       { At = q_t; Bt = wcat_t; bias = biascat; Cc = qo;    Nst = 384; tb = (y - 2) * 2 + wcol; }
    const int ta = bx * 2 + wrow;

    char* myst = smem + wave * 16384;
    const __half* abase = At + (size_t)ta * 16384 + lane * 8;
    const __half* bbase = Bt + (size_t)tb * 16384 + lane * 8;

    auto issue = [&](int stage, int kc) {
        char* sa = myst + stage * 8192;
        #pragma unroll
        for (int g = 0; g < 4; ++g) GLDS(abase + kc * 2048 + g * 512, sa + g * 1024);
        #pragma unroll
        for (int g = 0; g < 4; ++g) GLDS(bbase + kc * 2048 + g * 512, sa + 4096 + g * 1024);
    };

    f32x4 acc[4][4] = {};
    issue(0, 0);
    issue(1, 1);
    #pragma unroll
    for (int it = 0; it < 8; ++it) {
        if (it < 7) asm volatile("s_waitcnt vmcnt(8)" ::: "memory");
        else        asm volatile("s_waitcnt vmcnt(0)" ::: "memory");
        const char* sa = myst + (it & 1) * 8192;
        const char* sb = sa + 4096;
        f16x8 af[4], bfr[4];
        #pragma unroll
        for (int mi = 0; mi < 4; ++mi)
            af[mi] = *(const f16x8*)(sa + qk * 1024 + (mi * 16 + lr16) * 16);
        #pragma unroll
        for (int ni = 0; ni < 4; ++ni)
            bfr[ni] = *(const f16x8*)(sb + qk * 1024 + (ni * 16 + lr16) * 16);
        asm volatile("s_waitcnt lgkmcnt(0)" ::: "memory");  // frags in VGPRs before DMA overwrite
        if (it + 2 < 8) issue(it & 1, it + 2);
        #pragma unroll
        for (int mi = 0; mi < 4; ++mi)
            #pragma unroll
            for (int ni = 0; ni < 4; ++ni)
                acc[mi][ni] = __builtin_amdgcn_mfma_f32_16x16x32_f16(
                    af[mi], bfr[ni], acc[mi][ni], 0, 0, 0);
    }

    // wave-private epilogue: 64x64 fp16 transpose (stride 72 halves) -> dwordx4 stores
    const int colbase = tb * 64;
    float bv[4];
    #pragma unroll
    for (int ni = 0; ni < 4; ++ni) bv[ni] = bias[colbase + ni * 16 + lr16];
    __half* ep = (__half*)myst;
    #pragma unroll
    for (int mi = 0; mi < 4; ++mi)
        #pragma unroll
        for (int ni = 0; ni < 4; ++ni)
            #pragma unroll
            for (int r = 0; r < 4; ++r)
                ep[(mi * 16 + qk * 4 + r) * 72 + ni * 16 + lr16] =
                    __float2half(acc[mi][ni][r] + bv[ni]);
    const int er = lane >> 3, ec = (lane & 7) * 8;
    #pragma unroll
    for (int pass = 0; pass < 8; ++pass) {
        const int r = pass * 8 + er;
        const int4 vv = *(const int4*)&ep[r * 72 + ec];
        const int grow = bx * 128 + wrow * 64 + r;
        *(int4*)&Cc[(size_t)grow * Nst + colbase + ec] = vv;
    }
}

// ---------------- MSDA core + fused output GEMM ----------------
// Phases 1-2 as before; phase 3 computes out = core @ W_out^T + b_out via the
// D-transpose trick: A = W_out (m=ch_out) streamed from L2, B = core tile in
// LDS (n=query), D cols = queries -> coalesced float4 stores to d_out.
__global__ __launch_bounds__(256, 4) void msda_core_kernel(
    const __half* __restrict__ vproj,   // (bs*nv, 256) fp16
    const float* __restrict__ refp,     // (M, 8)
    const __half* __restrict__ qo,      // (M_PAD, 384): [0,256)=offsets, [256,384)=logits
    const __half* __restrict__ wo_h,    // (256, 256) fp16 row-major
    const float* __restrict__ b_out,
    float* __restrict__ out,            // (M, 256) fp32
    int nq, int nv, int M)
{
    const int bq0 = blockIdx.x * NQPB;
    const int t = threadIdx.x;

    __shared__ float s_w[NQPB * 128];
    __shared__ float s_ref[NQPB * 8];
    __shared__ __align__(16) unsigned int s_tap[NQPB * 8][68];
    __shared__ __align__(16) __half s_core[16 * 272];   // 272-half stride; rows 8..15 unused

    #pragma unroll
    for (int i = 0; i < 4; ++i) {
        const int s = t + i * 256;          // [0,1024)
        const int q = s >> 7, r = s & 127;
        s_w[s] = __half2float(qo[(size_t)(bq0 + q) * 384 + 256 + r]);
    }
    if (t < NQPB * 8) {
        const int gq = min(bq0 + (t >> 3), M - 1);
        s_ref[t] = refp[(size_t)gq * 8 + (t & 7)];
    }
    __syncthreads();

    // softmax over 16 per (q,h)
    if (t < NQPB * 8) {
        const int base = (t >> 3) * 128 + (t & 7) * 16;
        float m = -1e30f;
        #pragma unroll
        for (int j = 0; j < 16; ++j) m = fmaxf(m, s_w[base + j]);
        float e[16]; float ssum = 0.f;
        #pragma unroll
        for (int j = 0; j < 16; ++j) { e[j] = expf(s_w[base + j] - m); ssum += e[j]; }
        const float inv = 1.f / ssum;
        #pragma unroll
        for (int j = 0; j < 16; ++j) s_w[base + j] = e[j] * inv;
    }
    __syncthreads();

    // phase 1: tap precompute — 1024 samples, 4 per thread
    #pragma unroll
    for (int i = 0; i < 4; ++i) {
        const int s = t + i * 256;
        const int q = s >> 7, r = s & 127;
        const int h = r >> 4, lp = r & 15, l = lp >> 2;
        const int gq = bq0 + q;             // < M_PAD: qo is padded
        const float2 off = __half22float2(*(const __half2*)&qo[(size_t)gq * 384 + r * 2]);
        const float rx = s_ref[q * 8 + l * 2];
        const float ry = s_ref[q * 8 + l * 2 + 1];
        const int W = c_W[l], H = c_H[l], st = c_ST[l];
        const float fW = (float)W, fH = (float)H;
        const float lx = (rx + off.x / fW) * fW - 0.5f;
        const float ly = (ry + off.y / fH) * fH - 0.5f;
        const float x0f = floorf(lx), y0f = floorf(ly);
        const float fx = lx - x0f, fy = ly - y0f;
        const int x0 = (int)x0f, y0 = (int)y0f;
        const float aw = s_w[s];
        const float wx[2] = {1.f - fx, fx};
        const float wy[2] = {1.f - fy, fy};
        #pragma unroll
        for (int dy = 0; dy < 2; ++dy) {
            #pragma unroll
            for (int dx = 0; dx < 2; ++dx) {
                const int xi = x0 + dx, yi = y0 + dy;
                const bool ok = (xi >= 0) & (xi < W) & (yi >= 0) & (yi < H);
                const unsigned int idx = ok ? (unsigned int)(st + yi * W + xi) : 0u;
                const float w = ok ? aw * wy[dy] * wx[dx] : 0.f;
                const unsigned int pw = (unsigned int)__half_as_ushort(__float2half(w));
                s_tap[q * 8 + h][lp * 4 + dy * 2 + dx] = idx | (pw << 16);
            }
        }
    }
    __syncthreads();

    // phase 2: gather + pk_fma_f16. 32 lanes/query: h 0..7, c8 0..3.
    {
        const int q   = t >> 5;
        const int l32 = t & 31;
        const int h   = l32 >> 2;
        const int c8  = l32 & 3;
        const int gq  = bq0 + q;
        const int b   = (gq >= nq) ? 1 : 0;
        const __half* __restrict__ vb = vproj + (size_t)b * nv * EMBED + h * 32 + c8 * 8;
        const uint4* __restrict__ tapq = (const uint4*)s_tap[q * 8 + h];

        __align__(16) __half2 acc2[4];
        #pragma unroll
        for (int i = 0; i < 4; ++i) acc2[i] = __float2half2_rn(0.f);

        #pragma unroll 2
        for (int g = 0; g < 16; ++g) {
            const uint4 tq = tapq[g];
            const int4 r0 = *(const int4*)(vb + (size_t)(tq.x & 0xFFFFu) * EMBED);
            const int4 r1 = *(const int4*)(vb + (size_t)(tq.y & 0xFFFFu) * EMBED);
            const int4 r2 = *(const int4*)(vb + (size_t)(tq.z & 0xFFFFu) * EMBED);
            const int4 r3 = *(const int4*)(vb + (size_t)(tq.w & 0xFFFFu) * EMBED);
            const __half2 w0 = __half2half2(__ushort_as_half((unsigned short)(tq.x >> 16)));
            const __half2 w1 = __half2half2(__ushort_as_half((unsigned short)(tq.y >> 16)));
            const __half2 w2 = __half2half2(__ushort_as_half((unsigned short)(tq.z >> 16)));
            const __half2 w3 = __half2half2(__ushort_as_half((unsigned short)(tq.w >> 16)));
            const __half2* h0 = (const __half2*)&r0;
            const __half2* h1 = (const __half2*)&r1;
            const __half2* h2 = (const __half2*)&r2;
            const __half2* h3 = (const __half2*)&r3;
            #pragma unroll
            for (int i = 0; i < 4; ++i) {
                acc2[i] = __hfma2(w0, h0[i], acc2[i]);
                acc2[i] = __hfma2(w1, h1[i], acc2[i]);
                acc2[i] = __hfma2(w2, h2[i], acc2[i]);
                acc2[i] = __hfma2(w3, h3[i], acc2[i]);
            }
        }
        // stash into core tile (lane-contiguous 16B writes)
        *(int4*)(s_core + q * 272 + h * 32 + c8 * 8) = *(const int4*)acc2;
    }
    __syncthreads();

    // phase 3: fused out-GEMM. wave w -> ch_out [w*64, w*64+64).
    {
        const int w = t >> 6;
        const int lane = t & 63;
        const int lr16 = lane & 15, qk = lane >> 4;
        const char* cb = (const char*)s_core;
        f32x4 oacc[4] = {};
        #pragma unroll 2
        for (int kit = 0; kit < 8; ++kit) {
            const f16x8 bfrag = *(const f16x8*)(cb + lr16 * 544 + kit * 64 + qk * 16);
            #pragma unroll
            for (int mi = 0; mi < 4; ++mi) {
                const f16x8 afrag = *(const f16x8*)(wo_h +
                    (size_t)(w * 64 + mi * 16 + lr16) * 256 + kit * 32 + qk * 8);
                oacc[mi] = __builtin_amdgcn_mfma_f32_16x16x32_f16(
                    afrag, bfrag, oacc[mi], 0, 0, 0);
            }
        }
        // D cols = queries (lane&15), rows = ch_out (qk*4 + r)
        const int gq2 = bq0 + lr16;
        if (lr16 < NQPB && gq2 < M) {
            #pragma unroll
            for (int mi = 0; mi < 4; ++mi) {
                const int col = w * 64 + mi * 16 + qk * 4;
                const float4 b4 = *(const float4*)&b_out[col];
                float4 o;
                o.x = oacc[mi][0] + b4.x; o.y = oacc[mi][1] + b4.y;
                o.z = oacc[mi][2] + b4.z; o.w = oacc[mi][3] + b4.w;
                *(float4*)&out[(size_t)gq2 * 256 + col] = o;
            }
        }
    }
}

// ---------------- launch ----------------
extern "C" void kernel_launch(void* const* d_in, const int* in_sizes, int n_in,
                              void* d_out, int out_size, void* d_ws, size_t ws_size,
                              hipStream_t stream) {
    const float* query  = (const float*)d_in[0];
    const float* refp   = (const float*)d_in[1];
    const float* value  = (const float*)d_in[2];
    const float* W_samp = (const float*)d_in[6];
    const float* b_samp = (const float*)d_in[7];
    const float* W_attn = (const float*)d_in[8];
    const float* b_attn = (const float*)d_in[9];
    const float* W_val  = (const float*)d_in[10];
    const float* b_val  = (const float*)d_in[11];
    const float* W_out  = (const float*)d_in[12];
    const float* b_out  = (const float*)d_in[13];
    float* out = (float*)d_out;

    const int M  = in_sizes[0] / EMBED;   // 26588
    const int nq = NV_PER_B;
    const int nv = NV_PER_B;
    const int Mp = M_PAD;

    // workspace carve-up (~62 MB)
    char* p = (char*)d_ws;
    __half* q_t    = (__half*)p; p += (size_t)Mp * 256 * 2;
    __half* v_t    = (__half*)p; p += (size_t)Mp * 256 * 2;
    __half* vproj  = (__half*)p; p += (size_t)Mp * 256 * 2;
    __half* qo     = (__half*)p; p += (size_t)Mp * 384 * 2;
    __half* wv_t   = (__half*)p; p += 65536 * 2;
    __half* wcat_t = (__half*)p; p += 98304 * 2;
    __half* wo_h   = (__half*)p; p += 65536 * 2;
    float*  biascat= (float*)p;  p += 384 * 4;

    dim3 blk(256);

    convert_kernel<<<dim3(6769), blk, 0, stream>>>(
        query, value, W_val, W_samp, W_attn, W_out, b_samp, b_attn,
        q_t, v_t, wv_t, wcat_t, wo_h, biascat, M);

    proj_gemm_kernel<<<dim3(Mp / 128, 5), blk, 0, stream>>>(
        q_t, v_t, wv_t, wcat_t, b_val, biascat, vproj, qo);

    msda_core_kernel<<<dim3((M + NQPB - 1) / NQPB), blk, 0, stream>>>(
        vproj, refp, qo, wo_h, b_out, out, nq, nv, M);
}

// Round 9
// 217.516 us; speedup vs baseline: 1.0907x; 1.0907x over previous
//
#include <hip/hip_runtime.h>
#include <hip/hip_fp16.h>
#include <cstdint>
#include <cstddef>

// Problem constants (fixed by reference setup_inputs)
#define EMBED  256
#define NV_PER_B 13294
#define M_PAD   26624          // 416 * 64
#define NQPB   8               // queries per msda block

// Spatial pyramid (structural constants from reference SHAPES)
__constant__ const int c_H[4]  = {100, 50, 25, 13};
__constant__ const int c_W[4]  = {100, 50, 25, 13};
__constant__ const int c_ST[4] = {0, 10000, 12500, 13125};

typedef _Float16 f16x8 __attribute__((ext_vector_type(8)));
typedef float f32x4 __attribute__((ext_vector_type(4)));

#define GLDS(g, l) __builtin_amdgcn_global_load_lds( \
    (const __attribute__((address_space(1))) void*)(g), \
    (__attribute__((address_space(3))) void*)(l), 16, 0, 0)

// Tiled fp16 operand layout: halves offset = tile*16384 + kc*2048 + g*512 + row*8 + j
// (row = r%64, tile = r/64, k = kc*32 + g*8 + j). GLDS bursts are contiguous 1KB;
// LDS image is k-major so frag ds_read_b128 is lane-contiguous (conflict-free).

// ---------------- convert: fp32 -> tiled fp16 (q, v, W_val, W_cat, W_out) ----------------
__global__ __launch_bounds__(256) void convert_kernel(
    const float* __restrict__ q,  const float* __restrict__ v,
    const float* __restrict__ wv, const float* __restrict__ wsamp,
    const float* __restrict__ wattn, const float* __restrict__ wo,
    const float* __restrict__ bsamp, const float* __restrict__ battn,
    __half* __restrict__ q_t, __half* __restrict__ v_t,
    __half* __restrict__ wv_t, __half* __restrict__ wcat_t,
    __half* __restrict__ wo_t, float* __restrict__ biascat, int M)
{
    __shared__ float ls[64][36];
    const int id = blockIdx.x, t = threadIdx.x;

    if (id == 6768) {
        if (t < 96) {   // bias_cat = [b_samp(256); b_attn(128)]
            const float4 a = (t < 64) ? ((const float4*)bsamp)[t]
                                      : ((const float4*)battn)[t - 64];
            ((float4*)biascat)[t] = a;
        }
        return;
    }

    const float* srcA; const float* srcB = nullptr;
    __half* dst; int tile, kc, vrows, part2 = 0;
    if (id < 6656) {           // q/v: 2 arrays x 416 tiles x 8 kc
        const int arr = id & 1, r = id >> 1;
        tile = r >> 3; kc = r & 7;
        srcA = arr ? v : q; dst = arr ? v_t : q_t; vrows = M;
    } else if (id < 6688) {    // W_val: 4 tiles x 8 kc
        const int r = id - 6656;
        tile = r >> 3; kc = r & 7;
        srcA = wv; dst = wv_t; vrows = 256;
    } else if (id < 6736) {    // W_cat = [W_samp;W_attn]: 6 tiles x 8 kc
        const int r = id - 6688;
        tile = r >> 3; kc = r & 7;
        srcA = wsamp; srcB = wattn; dst = wcat_t; vrows = 384; part2 = 1;
    } else {                   // W_out: 4 tiles x 8 kc
        const int r = id - 6736;
        tile = r >> 3; kc = r & 7;
        srcA = wo; dst = wo_t; vrows = 256;
    }

    const int row = t >> 2, kq = t & 3;
    const int gr = tile * 64 + row;
    float4 a = make_float4(0.f, 0.f, 0.f, 0.f);
    float4 b = make_float4(0.f, 0.f, 0.f, 0.f);
    if (gr < vrows) {
        const float* sp = (part2 && gr >= 256) ? (srcB + (size_t)(gr - 256) * 256)
                                               : (srcA + (size_t)gr * 256);
        a = *(const float4*)(sp + kc * 32 + kq * 8);
        b = *(const float4*)(sp + kc * 32 + kq * 8 + 4);
    }
    *(float4*)&ls[row][kq * 8]     = a;
    *(float4*)&ls[row][kq * 8 + 4] = b;
    __syncthreads();
    const int g = t >> 6, r2 = t & 63;
    __align__(16) __half h8[8];
    #pragma unroll
    for (int j = 0; j < 8; ++j) h8[j] = __float2half(ls[r2][g * 8 + j]);
    *(int4*)(dst + (size_t)tile * 16384 + kc * 2048 + g * 512 + r2 * 8) = *(const int4*)h8;
}

// ---------------- barrier-free wave K-loop on tiled operands ----------------
__device__ __forceinline__ void wave_kloop_t(
    const __half* __restrict__ abase, const __half* __restrict__ bbase,
    char* myst, f32x4 (&acc)[4][4], int lr16, int qk)
{
    auto issue = [&](int stage, int kc) {
        char* sa = myst + stage * 8192;
        #pragma unroll
        for (int g = 0; g < 4; ++g) GLDS(abase + kc * 2048 + g * 512, sa + g * 1024);
        #pragma unroll
        for (int g = 0; g < 4; ++g) GLDS(bbase + kc * 2048 + g * 512, sa + 4096 + g * 1024);
    };
    issue(0, 0);
    issue(1, 1);
    #pragma unroll
    for (int it = 0; it < 8; ++it) {
        if (it < 7) asm volatile("s_waitcnt vmcnt(8)" ::: "memory");
        else        asm volatile("s_waitcnt vmcnt(0)" ::: "memory");
        const char* sa = myst + (it & 1) * 8192;
        const char* sb = sa + 4096;
        f16x8 af[4], bfr[4];
        #pragma unroll
        for (int mi = 0; mi < 4; ++mi)
            af[mi] = *(const f16x8*)(sa + qk * 1024 + (mi * 16 + lr16) * 16);
        #pragma unroll
        for (int ni = 0; ni < 4; ++ni)
            bfr[ni] = *(const f16x8*)(sb + qk * 1024 + (ni * 16 + lr16) * 16);
        asm volatile("s_waitcnt lgkmcnt(0)" ::: "memory");  // frags in VGPRs before DMA overwrite
        if (it + 2 < 8) issue(it & 1, it + 2);
        #pragma unroll
        for (int mi = 0; mi < 4; ++mi)
            #pragma unroll
            for (int ni = 0; ni < 4; ++ni)
                acc[mi][ni] = __builtin_amdgcn_mfma_f32_16x16x32_f16(
                    af[mi], bfr[ni], acc[mi][ni], 0, 0, 0);
    }
}

// ---------------- proj GEMM: value->vproj (y=0,1), query->qo (y=2,3,4) ----------------
__global__ __launch_bounds__(256) void proj_gemm_kernel(
    const __half* __restrict__ q_t, const __half* __restrict__ v_t,
    const __half* __restrict__ wv_t, const __half* __restrict__ wcat_t,
    const float* __restrict__ b_val, const float* __restrict__ biascat,
    __half* __restrict__ vproj, __half* __restrict__ qo)
{
    __shared__ __align__(16) char smem[65536];   // 4 waves x 2 stages x 8KB
    const int t = threadIdx.x;
    const int wave = t >> 6, lane = t & 63;
    const int lr16 = lane & 15, qk = lane >> 4;
    const int wrow = wave & 1, wcol = wave >> 1;
    const int y = blockIdx.y, bx = blockIdx.x;

    const __half* At; const __half* Bt; const float* bias; __half* Cc; int Nst, tb;
    if (y < 2) { At = v_t; Bt = wv_t;   bias = b_val;   Cc = vproj; Nst = 256; tb = y * 2 + wcol; }
    else       { At = q_t; Bt = wcat_t; bias = biascat; Cc = qo;    Nst = 384; tb = (y - 2) * 2 + wcol; }
    const int ta = bx * 2 + wrow;

    char* myst = smem + wave * 16384;
    f32x4 acc[4][4] = {};
    wave_kloop_t(At + (size_t)ta * 16384 + lane * 8,
                 Bt + (size_t)tb * 16384 + lane * 8, myst, acc, lr16, qk);

    // wave-private epilogue: 64x64 fp16 transpose (stride 72 halves) -> dwordx4 stores
    const int colbase = tb * 64;
    float bv[4];
    #pragma unroll
    for (int ni = 0; ni < 4; ++ni) bv[ni] = bias[colbase + ni * 16 + lr16];
    __half* ep = (__half*)myst;
    #pragma unroll
    for (int mi = 0; mi < 4; ++mi)
        #pragma unroll
        for (int ni = 0; ni < 4; ++ni)
            #pragma unroll
            for (int r = 0; r < 4; ++r)
                ep[(mi * 16 + qk * 4 + r) * 72 + ni * 16 + lr16] =
                    __float2half(acc[mi][ni][r] + bv[ni]);
    const int er = lane >> 3, ec = (lane & 7) * 8;
    #pragma unroll
    for (int pass = 0; pass < 8; ++pass) {
        const int r = pass * 8 + er;
        const int4 vv = *(const int4*)&ep[r * 72 + ec];
        const int grow = ta * 64 + r;
        *(int4*)&Cc[(size_t)grow * Nst + colbase + ec] = vv;
    }
}

// ---------------- out GEMM: core_t(tiled fp16) @ W_out^T + b_out -> fp32 d_out ----------------
__global__ __launch_bounds__(256) void gemm_out_kernel(
    const __half* __restrict__ core_t, const __half* __restrict__ wo_t,
    const float* __restrict__ b_out, float* __restrict__ C, int M)
{
    __shared__ __align__(16) char smem[65536];
    const int t = threadIdx.x;
    const int wave = t >> 6, lane = t & 63;
    const int lr16 = lane & 15, qk = lane >> 4;
    const int wrow = wave & 1, wcol = wave >> 1;
    const int ta = blockIdx.x * 2 + wrow;
    const int tb = blockIdx.y * 2 + wcol;

    char* myst = smem + wave * 16384;
    f32x4 acc[4][4] = {};
    wave_kloop_t(core_t + (size_t)ta * 16384 + lane * 8,
                 wo_t + (size_t)tb * 16384 + lane * 8, myst, acc, lr16, qk);

    // wave-private fp32 epilogue: 4 passes of 16 rows (stride 68 f32)
    const int colbase = tb * 64;
    float bv[4];
    #pragma unroll
    for (int ni = 0; ni < 4; ++ni) bv[ni] = b_out[colbase + ni * 16 + lr16];
    float* ep = (float*)myst;
    const int er = lane >> 4, ec = (lane & 15) * 4;
    #pragma unroll
    for (int p = 0; p < 4; ++p) {   // pass p handles acc rows mi==p
        #pragma unroll
        for (int ni = 0; ni < 4; ++ni)
            #pragma unroll
            for (int r = 0; r < 4; ++r)
                ep[(qk * 4 + r) * 68 + ni * 16 + lr16] = acc[p][ni][r] + bv[ni];
        #pragma unroll
        for (int j = 0; j < 4; ++j) {
            const int r16 = j * 4 + er;
            const float4 vv = *(const float4*)&ep[r16 * 68 + ec];
            const int grow = ta * 64 + p * 16 + r16;
            if (grow < M)
                *(float4*)&C[(size_t)grow * 256 + colbase + ec] = vv;
        }
        asm volatile("s_waitcnt lgkmcnt(0)" ::: "memory");  // reads done before next pass
    }
}

// ---------------- MSDA sampling core (R7 form; tiled core store; split grid) ----------------
__global__ __launch_bounds__(256, 4) void msda_core_kernel(
    const __half* __restrict__ vproj,   // (bs*nv, 256) fp16 row-major
    const float* __restrict__ refp,     // (M, 8)
    const __half* __restrict__ qo,      // (M_PAD, 384): [0,256)=offsets, [256,384)=logits
    __half* __restrict__ core_t,        // tiled fp16
    int nq, int nv, int M, int bq_base)
{
    const int bq0 = (bq_base + blockIdx.x) * NQPB;
    const int t = threadIdx.x;

    __shared__ float s_w[NQPB * 128];
    __shared__ float s_ref[NQPB * 8];
    __shared__ __align__(16) unsigned int s_tap[NQPB * 8][68];

    #pragma unroll
    for (int i = 0; i < 4; ++i) {
        const int s = t + i * 256;          // [0,1024)
        const int q = s >> 7, r = s & 127;
        s_w[s] = __half2float(qo[(size_t)(bq0 + q) * 384 + 256 + r]);
    }
    if (t < NQPB * 8) {
        const int gq = min(bq0 + (t >> 3), M - 1);
        s_ref[t] = refp[(size_t)gq * 8 + (t & 7)];
    }
    __syncthreads();

    // softmax over 16 per (q,h)
    if (t < NQPB * 8) {
        const int base = (t >> 3) * 128 + (t & 7) * 16;
        float m = -1e30f;
        #pragma unroll
        for (int j = 0; j < 16; ++j) m = fmaxf(m, s_w[base + j]);
        float e[16]; float ssum = 0.f;
        #pragma unroll
        for (int j = 0; j < 16; ++j) { e[j] = expf(s_w[base + j] - m); ssum += e[j]; }
        const float inv = 1.f / ssum;
        #pragma unroll
        for (int j = 0; j < 16; ++j) s_w[base + j] = e[j] * inv;
    }
    __syncthreads();

    // phase 1: tap precompute — 1024 samples, 4 per thread
    #pragma unroll
    for (int i = 0; i < 4; ++i) {
        const int s = t + i * 256;
        const int q = s >> 7, r = s & 127;
        const int h = r >> 4, lp = r & 15, l = lp >> 2;
        const int gq = bq0 + q;             // < M_PAD: qo is padded
        const float2 off = __half22float2(*(const __half2*)&qo[(size_t)gq * 384 + r * 2]);
        const float rx = s_ref[q * 8 + l * 2];
        const float ry = s_ref[q * 8 + l * 2 + 1];
        const int W = c_W[l], H = c_H[l], st = c_ST[l];
        const float fW = (float)W, fH = (float)H;
        const float lx = (rx + off.x / fW) * fW - 0.5f;
        const float ly = (ry + off.y / fH) * fH - 0.5f;
        const float x0f = floorf(lx), y0f = floorf(ly);
        const float fx = lx - x0f, fy = ly - y0f;
        const int x0 = (int)x0f, y0 = (int)y0f;
        const float aw = s_w[s];
        const float wx[2] = {1.f - fx, fx};
        const float wy[2] = {1.f - fy, fy};
        #pragma unroll
        for (int dy = 0; dy < 2; ++dy) {
            #pragma unroll
            for (int dx = 0; dx < 2; ++dx) {
                const int xi = x0 + dx, yi = y0 + dy;
                const bool ok = (xi >= 0) & (xi < W) & (yi >= 0) & (yi < H);
                const unsigned int idx = ok ? (unsigned int)(st + yi * W + xi) : 0u;
                const float w = ok ? aw * wy[dy] * wx[dx] : 0.f;
                const unsigned int pw = (unsigned int)__half_as_ushort(__float2half(w));
                s_tap[q * 8 + h][lp * 4 + dy * 2 + dx] = idx | (pw << 16);
            }
        }
    }
    __syncthreads();

    // phase 2: gather + pk_fma_f16. 32 lanes/query: h 0..7, c8 0..3.
    const int q   = t >> 5;
    const int l32 = t & 31;
    const int h   = l32 >> 2;
    const int c8  = l32 & 3;
    const int gq  = bq0 + q;
    const int b   = (gq >= nq) ? 1 : 0;
    const __half* __restrict__ vb = vproj + (size_t)b * nv * EMBED + h * 32 + c8 * 8;
    const uint4* __restrict__ tapq = (const uint4*)s_tap[q * 8 + h];

    __align__(16) __half2 acc2[4];
    #pragma unroll
    for (int i = 0; i < 4; ++i) acc2[i] = __float2half2_rn(0.f);

    #pragma unroll 2
    for (int g = 0; g < 16; ++g) {
        const uint4 tq = tapq[g];
        const int4 r0 = *(const int4*)(vb + (size_t)(tq.x & 0xFFFFu) * EMBED);
        const int4 r1 = *(const int4*)(vb + (size_t)(tq.y & 0xFFFFu) * EMBED);
        const int4 r2 = *(const int4*)(vb + (size_t)(tq.z & 0xFFFFu) * EMBED);
        const int4 r3 = *(const int4*)(vb + (size_t)(tq.w & 0xFFFFu) * EMBED);
        const __half2 w0 = __half2half2(__ushort_as_half((unsigned short)(tq.x >> 16)));
        const __half2 w1 = __half2half2(__ushort_as_half((unsigned short)(tq.y >> 16)));
        const __half2 w2 = __half2half2(__ushort_as_half((unsigned short)(tq.z >> 16)));
        const __half2 w3 = __half2half2(__ushort_as_half((unsigned short)(tq.w >> 16)));
        const __half2* h0 = (const __half2*)&r0;
        const __half2* h1 = (const __half2*)&r1;
        const __half2* h2 = (const __half2*)&r2;
        const __half2* h3 = (const __half2*)&r3;
        #pragma unroll
        for (int i = 0; i < 4; ++i) {
            acc2[i] = __hfma2(w0, h0[i], acc2[i]);
            acc2[i] = __hfma2(w1, h1[i], acc2[i]);
            acc2[i] = __hfma2(w2, h2[i], acc2[i]);
            acc2[i] = __hfma2(w3, h3[i], acc2[i]);
        }
    }

    if (gq < M) {
        // tiled store: channel c = h*32 + c8*8 -> kc = h, g = c8
        const int tile = gq >> 6, row = gq & 63;
        *(int4*)(core_t + (size_t)tile * 16384 + h * 2048 + c8 * 512 + row * 8) =
            *(const int4*)acc2;
    }
}

// ---------------- launch ----------------
extern "C" void kernel_launch(void* const* d_in, const int* in_sizes, int n_in,
                              void* d_out, int out_size, void* d_ws, size_t ws_size,
                              hipStream_t stream) {
    const float* query  = (const float*)d_in[0];
    const float* refp   = (const float*)d_in[1];
    const float* value  = (const float*)d_in[2];
    const float* W_samp = (const float*)d_in[6];
    const float* b_samp = (const float*)d_in[7];
    const float* W_attn = (const float*)d_in[8];
    const float* b_attn = (const float*)d_in[9];
    const float* W_val  = (const float*)d_in[10];
    const float* b_val  = (const float*)d_in[11];
    const float* W_out  = (const float*)d_in[12];
    const float* b_out  = (const float*)d_in[13];
    float* out = (float*)d_out;

    const int M  = in_sizes[0] / EMBED;   // 26588
    const int nq = NV_PER_B;
    const int nv = NV_PER_B;
    const int Mp = M_PAD;

    // workspace carve-up (~76 MB)
    char* p = (char*)d_ws;
    __half* q_t    = (__half*)p; p += (size_t)Mp * 256 * 2;
    __half* v_t    = (__half*)p; p += (size_t)Mp * 256 * 2;
    __half* vproj  = (__half*)p; p += (size_t)Mp * 256 * 2;
    __half* core_t = (__half*)p; p += (size_t)Mp * 256 * 2;
    __half* qo     = (__half*)p; p += (size_t)Mp * 384 * 2;
    __half* wv_t   = (__half*)p; p += 65536 * 2;
    __half* wcat_t = (__half*)p; p += 98304 * 2;
    __half* wo_t   = (__half*)p; p += 65536 * 2;
    float*  biascat= (float*)p;  p += 384 * 4;

    dim3 blk(256);

    convert_kernel<<<dim3(6769), blk, 0, stream>>>(
        query, value, W_val, W_samp, W_attn, W_out, b_samp, b_attn,
        q_t, v_t, wv_t, wcat_t, wo_t, biascat, M);

    proj_gemm_kernel<<<dim3(Mp / 128, 5), blk, 0, stream>>>(
        q_t, v_t, wv_t, wcat_t, b_val, biascat, vproj, qo);

    // split msda: two half-grids so proj/convert/out surface in top-5 counters
    const int nblk = (M + NQPB - 1) / NQPB;       // 3324
    const int half = nblk / 2;
    msda_core_kernel<<<dim3(half), blk, 0, stream>>>(
        vproj, refp, qo, core_t, nq, nv, M, 0);
    msda_core_kernel<<<dim3(nblk - half), blk, 0, stream>>>(
        vproj, refp, qo, core_t, nq, nv, M, half);

    gemm_out_kernel<<<dim3(Mp / 128, 2), blk, 0, stream>>>(
        core_t, wo_t, b_out, out, M);
}